// Round 4
// baseline (13803.966 us; speedup 1.0000x reference)
//
#include <hip/hip_runtime.h>
#include <hip/hip_bf16.h>

typedef __bf16 bf16x8 __attribute__((ext_vector_type(8)));
typedef float  f32x4  __attribute__((ext_vector_type(4)));

#define MFMA_BF16(a, b, c) __builtin_amdgcn_mfma_f32_16x16x32_bf16((a), (b), (c), 0, 0, 0)

constexpr int TT = 160, BB = 2048, HH = 512, EE = 64, VV = 128, G3 = 1536;
constexpr size_t LPROB_ELEMS = (size_t)TT * BB * VV;  // 41,943,040
constexpr int RB = 32;                // rows (batch) per block
constexpr int NBLK = BB / RB;         // 64 blocks
constexpr int HCH = 528;              // LDS h chunk stride: 32 rows*16B + 16B pad

__device__ __forceinline__ float fsigmoid(float x) {
  return 1.0f / (1.0f + __expf(-x));
}
__device__ __forceinline__ float ftanh(float x) {
  float ax = fabsf(x);
  float e = __expf(-2.0f * ax);
  float r = (1.0f - e) / (1.0f + e);
  return x < 0.0f ? -r : r;
}
// dual-dtype scalar load: isbf ? bf16[i] : f32[i]
__device__ __forceinline__ float ld(const void* p, long i, int isbf) {
  return isbf ? (float)((const __bf16*)p)[i] : ((const float*)p)[i];
}

// h LDS layout: k-chunked [64 chunks][32 rows][8 cols] bf16, chunk stride 528B.
// A-frag read (16 lanes, rows 0..15, one 16B chunk) -> conflict-free (132-dword
// chunk stride => 4-bank rotation per quad, each bank hit exactly 2x per wave).
__device__ __forceinline__ int hoff(int row, int ce) {
  return (ce >> 3) * HCH + row * 16 + ((ce & 7) << 1);
}

// ---------------- dtype probe ----------------
__global__ __launch_bounds__(256) void probe_dtype(
    const unsigned short* __restrict__ eh, int* __restrict__ flagp) {
  __shared__ int sb[256];
  int tid = threadIdx.x;
  int cnt = 0;
  for (int i = tid; i < 4096; i += 256) {
    unsigned short u = eh[i];
    int e = (u >> 7) & 0xFF;
    if ((u & 0x7FFF) == 0 || (e >= 90 && e <= 150)) cnt++;
  }
  sb[tid] = cnt;
  __syncthreads();
  for (int s = 128; s > 0; s >>= 1) {
    if (tid < s) sb[tid] += sb[tid + s];
    __syncthreads();
  }
  if (tid == 0) *flagp = (sb[0] > 3072) ? 1 : 0;
}

// ---------------- prep kernels ----------------
__global__ __launch_bounds__(256) void conv_w(
    const void* __restrict__ Whh, const void* __restrict__ Wout,
    const void* __restrict__ bhh, const void* __restrict__ bout,
    const int* __restrict__ flagp,
    __bf16* __restrict__ Whh_b, __bf16* __restrict__ Wout_b,
    float* __restrict__ bhhn_f, float* __restrict__ bout_f) {
  const int isbf = *flagp;
  int idx = blockIdx.x * 256 + threadIdx.x;   // 3072 blocks -> 786,432 = 1536*512
  Whh_b[idx] = (__bf16)ld(Whh, idx, isbf);
  if (idx < VV * HH) Wout_b[idx] = (__bf16)ld(Wout, idx, isbf);
  if (idx < HH) bhhn_f[idx] = ld(bhh, 2 * HH + idx, isbf);
  if (idx < VV) bout_f[idx] = ld(bout, idx, isbf);
}

// gi planes: gi[g][v][c] = relu(emb[v]).W_ih[g*512+c] + b_ih[g*512+c] + (g<2 ? b_hh[..] : 0)
// Plane-separated layout: epilogue reads gi_g[tk*512 + c] -> 16 lanes contiguous 64B.
__global__ __launch_bounds__(256) void prep_gi(
    const void* __restrict__ emb, const void* __restrict__ Wih,
    const void* __restrict__ bih, const void* __restrict__ bhh,
    const int* __restrict__ flagp, float* __restrict__ gi) {
  const int isbf = *flagp;
  int idx = blockIdx.x * 256 + threadIdx.x;   // 768 blocks -> exactly 128*1536
  int v = idx / G3;
  int n = idx - v * G3;
  float s = 0.0f;
#pragma unroll 8
  for (int k = 0; k < EE; ++k) {
    float x = ld(emb, v * EE + k, isbf);
    x = x > 0.0f ? x : 0.0f;
    s += x * ld(Wih, (long)n * EE + k, isbf);
  }
  s += ld(bih, n, isbf);
  if (n < 2 * HH) s += ld(bhh, n, isbf);
  int g = n >> 9;        // gate 0..2 (r,z,n)
  int c = n & 511;       // col 0..511
  gi[((size_t)g * VV + v) * HH + c] = s;
}

// ---------------- fused persistent kernel (no inter-block sync) ----------------
// 64 blocks x 512 threads (8 waves), __launch_bounds__(512,2) -> 256 VGPR/thread.
// Block bid owns batch rows [bid*32, bid*32+32) for the entire 160-step
// recurrence + logits + log_softmax. h bf16 double-buffered in LDS (2 barriers
// per step); h f32 in registers. Wave w owns h-cols [w*64,(w+1)*64): GRU acc
// 2m x 3g x 4ct = 96 VGPR; K-loop fully unrolled, 12 B-pointers + immediate
// offsets -> compiler can keep ~20 1KB loads in flight (load-port saturation
// is the whole game: 1.9 MB/step/CU from L2 is the structural floor).
__global__ __launch_bounds__(512, 2) void gru_fused(
    const __bf16* __restrict__ Whh, const __bf16* __restrict__ Wout,
    const float* __restrict__ bhhn_f, const float* __restrict__ bout_f,
    const float* __restrict__ gi, const int* __restrict__ tgt,
    const int* __restrict__ flagp, const void* __restrict__ ehid,
    void* __restrict__ outp) {
  __shared__ __align__(16) char hlds[2][64 * HCH];  // 2 x 33,792 B  h bf16 ping/pong
  __shared__ float llds[RB * 132];                  // 16,896 B  logits staging

  const int tid = threadIdx.x;
  const int bid = blockIdx.x;
  const int rBase = bid * RB;
  const int w = tid >> 6;          // wave 0..7
  const int lane = tid & 63;
  const int q = lane >> 4;
  const int l16 = lane & 15;
  const int isbf = *flagp;
  const f32x4 fzero = {0.0f, 0.0f, 0.0f, 0.0f};

  // ---- prologue: h0 -> LDS buf0 (bf16) + registers (f32, owned) ----
  for (int i = tid; i < RB * HH; i += 512) {
    int row = i >> 9, ce = i & 511;
    float v = ld(ehid, (long)(rBase + row) * HH + ce, isbf);
    *(__bf16*)(hlds[0] + hoff(row, ce)) = (__bf16)v;
  }
  // thread-owned f32 state: rows m*16+q*4+rg, cols w*64+ct*16+l16
  float hreg[2][4][4];   // [m][ct][rg]
#pragma unroll
  for (int m = 0; m < 2; ++m)
#pragma unroll
    for (int ct = 0; ct < 4; ++ct)
#pragma unroll
      for (int rg = 0; rg < 4; ++rg) {
        int row = m * 16 + q * 4 + rg;
        int c = w * 64 + ct * 16 + l16;
        hreg[m][ct][rg] = ld(ehid, (long)(rBase + row) * HH + c, isbf);
      }
  __syncthreads();

  // hoisted B pointers: 12 GRU tiles (gate g, col-subtile ct), rows of Whh
  const __bf16* bp[3][4];
#pragma unroll
  for (int g = 0; g < 3; ++g)
#pragma unroll
    for (int ct = 0; ct < 4; ++ct)
      bp[g][ct] = Whh + (size_t)(g * HH + w * 64 + ct * 16 + l16) * HH + q * 8;

  float bh[4];
#pragma unroll
  for (int ct = 0; ct < 4; ++ct) bh[ct] = bhhn_f[w * 64 + ct * 16 + l16];

  // logits: wave -> (m-tile mw, vocab tiles nv and nv+4)
  const int mw = w >> 2;           // 0..1
  const int nv = w & 3;            // 0..3
  const __bf16* bpo0 = Wout + (size_t)(nv * 16 + l16) * HH + q * 8;
  const __bf16* bpo1 = bpo0 + (size_t)64 * HH;
  const float boL0 = bout_f[nv * 16 + l16];
  const float boL1 = bout_f[64 + nv * 16 + l16];

  for (int s = 0; s < TT; ++s) {
    const int p = s & 1;           // read buffer; write 1-p
    const char* hr = hlds[p];
    char* hw = hlds[1 - p];

    // ---- token prefetch (independent of h; K-loop hides the latency) ----
    int tk[2][4];
#pragma unroll
    for (int m = 0; m < 2; ++m)
#pragma unroll
      for (int rg = 0; rg < 4; ++rg) {
        int row = m * 16 + q * 4 + rg;
        tk[m][rg] = (s == 0) ? 0 : tgt[(long)(rBase + row) * TT + (s - 1)];
      }

    // ---- gh = h(t-1) @ Whh^T : 32 rows x (3 gates x 64 cols) per wave ----
    f32x4 acc[2][3][4];   // [m][gate][ct]
#pragma unroll
    for (int m = 0; m < 2; ++m)
#pragma unroll
      for (int g = 0; g < 3; ++g)
#pragma unroll
        for (int ct = 0; ct < 4; ++ct) acc[m][g][ct] = fzero;

#pragma unroll
    for (int k0 = 0; k0 < HH; k0 += 32) {
      const int kb = ((k0 >> 3) + q) * HCH + l16 * 16;
      bf16x8 a0 = *(const bf16x8*)(hr + kb);
      bf16x8 a1 = *(const bf16x8*)(hr + kb + 256);
#pragma unroll
      for (int g = 0; g < 3; ++g)
#pragma unroll
        for (int ct = 0; ct < 4; ++ct) {
          bf16x8 b = *(const bf16x8*)(bp[g][ct] + k0);
          acc[0][g][ct] = MFMA_BF16(a0, b, acc[0][g][ct]);
          acc[1][g][ct] = MFMA_BF16(a1, b, acc[1][g][ct]);
        }
    }

    // ---- GRU epilogue: f32 state in regs; write h(t) bf16 to LDS buf 1-p ----
#pragma unroll
    for (int m = 0; m < 2; ++m)
#pragma unroll
      for (int rg = 0; rg < 4; ++rg) {
        const int row = m * 16 + q * 4 + rg;
        const float* g0 = gi + (size_t)tk[m][rg] * HH;              // plane r
        const float* g1 = g0 + (size_t)VV * HH;                     // plane z
        const float* g2 = g1 + (size_t)VV * HH;                     // plane n
#pragma unroll
        for (int ct = 0; ct < 4; ++ct) {
          const int c = w * 64 + ct * 16 + l16;
          float r_ = fsigmoid(acc[m][0][ct][rg] + g0[c]);
          float z_ = fsigmoid(acc[m][1][ct][rg] + g1[c]);
          float n_ = ftanh(g2[c] + r_ * (acc[m][2][ct][rg] + bh[ct]));
          float hv = (1.0f - z_) * n_ + z_ * hreg[m][ct][rg];
          hreg[m][ct][rg] = hv;
          *(__bf16*)(hw + hoff(row, c)) = (__bf16)hv;
        }
      }
    __syncthreads();   // bar1: h(t) LDS ready (also covers llds WAR from s-1)

    // ---- logits = h(t) @ Wout^T : per wave 16 rows x 2 vocab tiles ----
    f32x4 acc2[2];
    acc2[0] = fzero; acc2[1] = fzero;
#pragma unroll
    for (int k0 = 0; k0 < HH; k0 += 32) {
      bf16x8 a = *(const bf16x8*)(hw + ((k0 >> 3) + q) * HCH + (mw * 16 + l16) * 16);
      acc2[0] = MFMA_BF16(a, *(const bf16x8*)(bpo0 + k0), acc2[0]);
      acc2[1] = MFMA_BF16(a, *(const bf16x8*)(bpo1 + k0), acc2[1]);
    }
    {
      const int col = nv * 16 + l16;
#pragma unroll
      for (int rg = 0; rg < 4; ++rg) {
        llds[(mw * 16 + q * 4 + rg) * 132 + col] = acc2[0][rg] + boL0;
        llds[(mw * 16 + q * 4 + rg) * 132 + col + 64] = acc2[1][rg] + boL1;
      }
    }
    __syncthreads();   // bar2: logits staged

    // ---- log_softmax: 32 rows x 16 segs = all 512 threads ----
    {
      int row = tid >> 4, seg = tid & 15;
      const float* lr = &llds[row * 132 + seg * 8];
      float x[8];
      float m = -3.0e38f;
#pragma unroll
      for (int i = 0; i < 8; ++i) { x[i] = lr[i]; m = fmaxf(m, x[i]); }
#pragma unroll
      for (int d = 1; d < 16; d <<= 1) m = fmaxf(m, __shfl_xor(m, d, 16));
      float ssum = 0.0f;
#pragma unroll
      for (int i = 0; i < 8; ++i) ssum += __expf(x[i] - m);
#pragma unroll
      for (int d = 1; d < 16; d <<= 1) ssum += __shfl_xor(ssum, d, 16);
      float lg = m + __logf(ssum);
      size_t ofs = (size_t)s * (BB * VV) + (size_t)(rBase + row) * VV + seg * 8;
      if (isbf) {
        bf16x8 ov;
#pragma unroll
        for (int i = 0; i < 8; ++i) ov[i] = (__bf16)(x[i] - lg);
        *(bf16x8*)((__bf16*)outp + ofs) = ov;
      } else {
        f32x4 o0, o1;
#pragma unroll
        for (int i = 0; i < 4; ++i) { o0[i] = x[i] - lg; o1[i] = x[4 + i] - lg; }
        float* dst = (float*)outp + ofs;
        *(f32x4*)dst = o0;
        *(f32x4*)(dst + 4) = o1;
      }
    }
    // no 3rd barrier: next llds write sits behind next bar1, which every wave
    // can only reach after finishing this softmax.
  }

  // ---- final hidden h(160): exact f32 from registers -> output ----
#pragma unroll
  for (int m = 0; m < 2; ++m)
#pragma unroll
    for (int ct = 0; ct < 4; ++ct)
#pragma unroll
      for (int rg = 0; rg < 4; ++rg) {
        const int row = m * 16 + q * 4 + rg;
        const int c = w * 64 + ct * 16 + l16;
        size_t o = LPROB_ELEMS + (size_t)(rBase + row) * HH + c;
        if (isbf) ((__bf16*)outp)[o] = (__bf16)hreg[m][ct][rg];
        else      ((float*)outp)[o] = hreg[m][ct][rg];
      }
}

// ---------------- launcher ----------------
extern "C" void kernel_launch(void* const* d_in, const int* in_sizes, int n_in,
                              void* d_out, int out_size, void* d_ws, size_t ws_size,
                              hipStream_t stream) {
  // setup_inputs order:
  // 0 encoder_outputs (unused), 1 encoder_hidden, 2 target_tensor, 3 embedding,
  // 4 W_ih, 5 W_hh, 6 b_ih, 7 b_hh, 8 W_out, 9 b_out
  const void* ehid = d_in[1];
  const int*  tgt  = (const int*)d_in[2];
  const void* emb  = d_in[3];
  const void* Wih  = d_in[4];
  const void* Whh  = d_in[5];
  const void* bih  = d_in[6];
  const void* bhh  = d_in[7];
  const void* Wout = d_in[8];
  const void* bout = d_in[9];

  // workspace carve (~2.5 MiB), all offsets 256B-aligned
  char* ws = (char*)d_ws;
  int*    flagp  = (int*)(ws + 0);              //       256 B
  float*  gi     = (float*)(ws + 256);          //   786,432 B: [3][128][512] f32
  __bf16* Whh_b  = (__bf16*)(ws + 786688);      // 1,572,864 B
  __bf16* Wout_b = (__bf16*)(ws + 2359552);     //   131,072 B
  float*  bhhn_f = (float*)(ws + 2490624);      //     2,048 B
  float*  bout_f = (float*)(ws + 2492672);      //       512 B

  probe_dtype<<<1, 256, 0, stream>>>((const unsigned short*)ehid, flagp);
  conv_w<<<3072, 256, 0, stream>>>(Whh, Wout, bhh, bout, flagp,
                                   Whh_b, Wout_b, bhhn_f, bout_f);
  prep_gi<<<768, 256, 0, stream>>>(emb, Wih, bih, bhh, flagp, gi);

  gru_fused<<<NBLK, 512, 0, stream>>>(Whh_b, Wout_b, bhhn_f, bout_f, gi, tgt,
                                      flagp, ehid, d_out);
}

// Round 5
// 9500.466 us; speedup vs baseline: 1.4530x; 1.4530x over previous
//
#include <hip/hip_runtime.h>
#include <hip/hip_bf16.h>

typedef __bf16 bf16x8 __attribute__((ext_vector_type(8)));
typedef float  f32x4  __attribute__((ext_vector_type(4)));

#define MFMA_BF16(a, b, c) __builtin_amdgcn_mfma_f32_16x16x32_bf16((a), (b), (c), 0, 0, 0)

constexpr int TT = 160, BB = 2048, HH = 512, EE = 64, VV = 128, G3 = 1536;
constexpr size_t LPROB_ELEMS = (size_t)TT * BB * VV;  // 41,943,040

__device__ __forceinline__ float fsigmoid(float x) {
  return 1.0f / (1.0f + __expf(-x));
}
__device__ __forceinline__ float ftanh(float x) {
  float ax = fabsf(x);
  float e = __expf(-2.0f * ax);
  float r = (1.0f - e) / (1.0f + e);
  return x < 0.0f ? -r : r;
}
// dual-dtype scalar load: isbf ? bf16[i] : f32[i]
__device__ __forceinline__ float ld(const void* p, long i, int isbf) {
  return isbf ? (float)((const __bf16*)p)[i] : ((const float*)p)[i];
}

// ---------------- dtype probe + barrier init ----------------
__global__ __launch_bounds__(256) void probe_dtype(
    const unsigned short* __restrict__ eh, int* __restrict__ flagp,
    unsigned* __restrict__ bar) {
  __shared__ int sb[256];
  int tid = threadIdx.x;
  for (int i = tid; i < 1024; i += 256) bar[i] = 0u;   // leaves+root+gen
  int cnt = 0;
  for (int i = tid; i < 4096; i += 256) {
    unsigned short u = eh[i];
    int e = (u >> 7) & 0xFF;
    if ((u & 0x7FFF) == 0 || (e >= 90 && e <= 150)) cnt++;
  }
  sb[tid] = cnt;
  __syncthreads();
  for (int s = 128; s > 0; s >>= 1) {
    if (tid < s) sb[tid] += sb[tid + s];
    __syncthreads();
  }
  if (tid == 0) *flagp = (sb[0] > 3072) ? 1 : 0;
}

// ---------------- prep kernels ----------------
__global__ __launch_bounds__(256) void conv_w(
    const void* __restrict__ Whh, const void* __restrict__ Wout,
    const void* __restrict__ bhh, const void* __restrict__ bout,
    const int* __restrict__ flagp,
    __bf16* __restrict__ Whh_b, __bf16* __restrict__ Wout_b,
    float* __restrict__ bhhn_f, float* __restrict__ bout_f) {
  const int isbf = *flagp;
  int idx = blockIdx.x * 256 + threadIdx.x;   // 3072 blocks -> 786,432 = 1536*512
  Whh_b[idx] = (__bf16)ld(Whh, idx, isbf);
  if (idx < VV * HH) Wout_b[idx] = (__bf16)ld(Wout, idx, isbf);
  if (idx < HH) bhhn_f[idx] = ld(bhh, 2 * HH + idx, isbf);
  if (idx < VV) bout_f[idx] = ld(bout, idx, isbf);
}

// gi_vocab[v][n] = relu(emb[v]) . W_ih[n] + b_ih[n] + (n < 1024 ? b_hh[n] : 0)
__global__ __launch_bounds__(256) void prep_gi(
    const void* __restrict__ emb, const void* __restrict__ Wih,
    const void* __restrict__ bih, const void* __restrict__ bhh,
    const int* __restrict__ flagp, float* __restrict__ gi) {
  const int isbf = *flagp;
  int idx = blockIdx.x * 256 + threadIdx.x;   // 768 blocks -> exactly 128*1536
  int v = idx / G3;
  int n = idx - v * G3;
  float s = 0.0f;
#pragma unroll 8
  for (int k = 0; k < EE; ++k) {
    float x = ld(emb, v * EE + k, isbf);
    x = x > 0.0f ? x : 0.0f;
    s += x * ld(Wih, (long)n * EE + k, isbf);
  }
  s += ld(bih, n, isbf);
  if (n < 2 * HH) s += ld(bhh, n, isbf);
  gi[idx] = s;
}

// h0 bf16 mirror (f32 state lives in phase-1 registers)
__global__ __launch_bounds__(256) void prep_hb0(
    const void* __restrict__ ehid, const int* __restrict__ flagp,
    __bf16* __restrict__ hb0) {
  const int isbf = *flagp;
  int idx = blockIdx.x * 256 + threadIdx.x;   // 4096 blocks
  hb0[idx] = (__bf16)ld(ehid, idx, isbf);
}

// ---------------- grid barrier (relaxed polls — the r1 fix) ----------------
// Two-level: 16 leaf counters (40 blocks each, 128B-separated) -> root -> gen.
// Arrivals are ACQ_REL RMWs (release publishes this block's h-writes via L2
// writeback; acquire chains the tree). gen store is RELEASE. Pollers use
// RELAXED agent loads (coherent LLC read, NO L2 invalidate per poll — r1's
// fatal mistake) and execute exactly ONE acquire fence after the spin exits.
// Counters are monotonic (thresholds scale with t): no reset races.
__device__ __forceinline__ void gridbar(unsigned* __restrict__ bar, int bid, int t) {
  __syncthreads();
  if (threadIdx.x == 0) {
    unsigned* leaf = bar + (bid & 15) * 32;   // 16 leaves, 128B apart
    unsigned* root = bar + 512;               // own 128B line
    unsigned* gen  = bar + 544;               // own 128B line
    __builtin_amdgcn_fence(__ATOMIC_RELEASE, "agent");
    unsigned lo = __hip_atomic_fetch_add(leaf, 1u, __ATOMIC_ACQ_REL,
                                         __HIP_MEMORY_SCOPE_AGENT);
    if (lo == (unsigned)(40 * (t + 1) - 1)) {
      unsigned ro = __hip_atomic_fetch_add(root, 1u, __ATOMIC_ACQ_REL,
                                           __HIP_MEMORY_SCOPE_AGENT);
      if (ro == (unsigned)(16 * (t + 1) - 1))
        __hip_atomic_store(gen, (unsigned)(t + 1), __ATOMIC_RELEASE,
                           __HIP_MEMORY_SCOPE_AGENT);
    }
    while (__hip_atomic_load(gen, __ATOMIC_RELAXED,
                             __HIP_MEMORY_SCOPE_AGENT) < (unsigned)(t + 1))
      __builtin_amdgcn_s_sleep(2);
    __builtin_amdgcn_fence(__ATOMIC_ACQUIRE, "agent");
  }
  __syncthreads();
}

// ---------------- persistent kernel (round-0 decomposition) ----------------
// Grid 640 x 256, ONE launch, 161 internal iterations separated by gridbar.
// Blocks [0,512): phase 1 — grp=bid&15 owns rows grp*128..+128, colTile=bid>>4
//   owns cols colTile*16..+16 of all 3 gates. h f32 state in registers.
//   t==160: write final hidden from registers.
// Blocks [512,640): phase 2 — logits + log_softmax of h(t-1), 16 rows each.
// Co-residency: 640 blocks at 256 thr, __launch_bounds__(256,4) => VGPR<=128
// => >=4 blocks/CU => 1024 slots (empirically proven co-resident in r1).
__global__ __launch_bounds__(256, 4) void gru_persist(
    const __bf16* __restrict__ Whh, const __bf16* __restrict__ Wout,
    const float* __restrict__ bhhn_f, const float* __restrict__ bout_f,
    const float* __restrict__ gi, const int* __restrict__ tgt,
    const int* __restrict__ flagp, const void* __restrict__ ehid,
    __bf16* __restrict__ hb0, __bf16* __restrict__ hb1,
    void* __restrict__ outp, unsigned* __restrict__ bar) {
  __shared__ float llds[16 * 132];   // phase-2 only (8448 B)

  const int tid = threadIdx.x;
  const int bid = blockIdx.x;
  const int w = tid >> 6;
  const int lane = tid & 63;
  const int q = lane >> 4;
  const int l16 = lane & 15;
  const int isbf = *flagp;
  const f32x4 fzero = {0.0f, 0.0f, 0.0f, 0.0f};

  if (bid < 512) {
    // ================= phase 1: GRU recurrence =================
    const int grp = bid & 15;
    const int colTile = bid >> 4;
    const int mBase = grp * 128 + w * 32;
    const int c = colTile * 16 + l16;
    const float bhhn = bhhn_f[c];
    const size_t aOff = (size_t)(mBase + l16) * HH + q * 8;
    const __bf16* bRow = Whh + (size_t)c * HH + q * 8;

    // thread-owned f32 state: rows mBase + ms*16 + q*4 + rg, column c
    float hreg[2][4];
#pragma unroll
    for (int ms = 0; ms < 2; ++ms)
#pragma unroll
      for (int rg = 0; rg < 4; ++rg) {
        int row = mBase + ms * 16 + q * 4 + rg;
        hreg[ms][rg] = ld(ehid, (long)row * HH + c, isbf);
      }

    for (int t = 0; t <= 160; ++t) {
      if (t < 160) {
        const __bf16* hbs = (t & 1) ? hb1 : hb0;   // h(t-1)
        __bf16* hbd = (t & 1) ? hb0 : hb1;         // h(t)

        f32x4 acc[2][3];
#pragma unroll
        for (int ms = 0; ms < 2; ++ms)
#pragma unroll
          for (int gg = 0; gg < 3; ++gg) acc[ms][gg] = fzero;

        const __bf16* aRow0 = hbs + aOff;
        const __bf16* aRow1 = aRow0 + 16 * HH;
#pragma unroll 4
        for (int k0 = 0; k0 < HH; k0 += 32) {
          bf16x8 a0 = *(const bf16x8*)(aRow0 + k0);
          bf16x8 a1 = *(const bf16x8*)(aRow1 + k0);
#pragma unroll
          for (int gg = 0; gg < 3; ++gg) {
            bf16x8 bf = *(const bf16x8*)(bRow + (size_t)gg * (HH * HH) + k0);
            acc[0][gg] = MFMA_BF16(a0, bf, acc[0][gg]);
            acc[1][gg] = MFMA_BF16(a1, bf, acc[1][gg]);
          }
        }

#pragma unroll
        for (int ms = 0; ms < 2; ++ms) {
#pragma unroll
          for (int rg = 0; rg < 4; ++rg) {
            int row = mBase + ms * 16 + q * 4 + rg;
            int tk = (t == 0) ? 0 : tgt[row * TT + (t - 1)];
            const float* gv = gi + (size_t)tk * G3 + c;
            float r_ = fsigmoid(acc[ms][0][rg] + gv[0]);
            float z_ = fsigmoid(acc[ms][1][rg] + gv[HH]);
            float n_ = ftanh(gv[2 * HH] + r_ * (acc[ms][2][rg] + bhhn));
            float hv = (1.0f - z_) * n_ + z_ * hreg[ms][rg];
            hreg[ms][rg] = hv;
            hbd[(size_t)row * HH + c] = (__bf16)hv;
          }
        }
      } else {
        // t == 160: final hidden straight from registers
#pragma unroll
        for (int ms = 0; ms < 2; ++ms)
#pragma unroll
          for (int rg = 0; rg < 4; ++rg) {
            int row = mBase + ms * 16 + q * 4 + rg;
            size_t o = LPROB_ELEMS + (size_t)row * HH + c;
            if (isbf) ((__bf16*)outp)[o] = (__bf16)hreg[ms][rg];
            else      ((float*)outp)[o] = hreg[ms][rg];
          }
      }
      if (t < 160) gridbar(bar, bid, t);
    }
  } else {
    // ================= phase 2: logits + log_softmax of h(t-1) =================
    const int rb = (bid - 512) * 16;
    const size_t aOffBase = (size_t)(rb + l16) * HH + q * 8;
    const __bf16* bR0 = Wout + (size_t)(w * 32 + l16) * HH + q * 8;
    const __bf16* bR1 = bR0 + 16 * HH;

    for (int t = 0; t <= 160; ++t) {
      if (t >= 1) {
        const __bf16* hbs = (t & 1) ? hb1 : hb0;   // h(t-1)
        const __bf16* aR = hbs + aOffBase;
        f32x4 acc2[2];
        acc2[0] = fzero; acc2[1] = fzero;
#pragma unroll 4
        for (int k0 = 0; k0 < HH; k0 += 32) {
          bf16x8 a  = *(const bf16x8*)(aR + k0);
          bf16x8 b0 = *(const bf16x8*)(bR0 + k0);
          bf16x8 b1 = *(const bf16x8*)(bR1 + k0);
          acc2[0] = MFMA_BF16(a, b0, acc2[0]);
          acc2[1] = MFMA_BF16(a, b1, acc2[1]);
        }
#pragma unroll
        for (int j = 0; j < 2; ++j) {
          int col = (w * 2 + j) * 16 + l16;
          float bo = bout_f[col];
#pragma unroll
          for (int rg = 0; rg < 4; ++rg)
            llds[(q * 4 + rg) * 132 + col] = acc2[j][rg] + bo;
        }
        __syncthreads();
        {
          int row = tid >> 4, seg = tid & 15;
          const float* lr = &llds[row * 132 + seg * 8];
          float x[8];
          float m = -3.0e38f;
#pragma unroll
          for (int i = 0; i < 8; ++i) { x[i] = lr[i]; m = fmaxf(m, x[i]); }
#pragma unroll
          for (int d = 1; d < 16; d <<= 1) m = fmaxf(m, __shfl_xor(m, d, 16));
          float s = 0.0f;
#pragma unroll
          for (int i = 0; i < 8; ++i) s += __expf(x[i] - m);
#pragma unroll
          for (int d = 1; d < 16; d <<= 1) s += __shfl_xor(s, d, 16);
          float lg = m + __logf(s);
          size_t ofs = (size_t)(t - 1) * (BB * VV) + (size_t)(rb + row) * VV + seg * 8;
          if (isbf) {
            bf16x8 ov;
#pragma unroll
            for (int i = 0; i < 8; ++i) ov[i] = (__bf16)(x[i] - lg);
            *(bf16x8*)((__bf16*)outp + ofs) = ov;
          } else {
            f32x4 o0, o1;
#pragma unroll
            for (int i = 0; i < 4; ++i) { o0[i] = x[i] - lg; o1[i] = x[4 + i] - lg; }
            float* dst = (float*)outp + ofs;
            *(f32x4*)dst = o0;
            *(f32x4*)(dst + 4) = o1;
          }
        }
        __syncthreads();   // llds reads done before next iteration's writes
      }
      if (t < 160) gridbar(bar, bid, t);
    }
  }
}

// ---------------- launcher ----------------
extern "C" void kernel_launch(void* const* d_in, const int* in_sizes, int n_in,
                              void* d_out, int out_size, void* d_ws, size_t ws_size,
                              hipStream_t stream) {
  // setup_inputs order:
  // 0 encoder_outputs (unused), 1 encoder_hidden, 2 target_tensor, 3 embedding,
  // 4 W_ih, 5 W_hh, 6 b_ih, 7 b_hh, 8 W_out, 9 b_out
  const void* ehid = d_in[1];
  const int*  tgt  = (const int*)d_in[2];
  const void* emb  = d_in[3];
  const void* Wih  = d_in[4];
  const void* Whh  = d_in[5];
  const void* bih  = d_in[6];
  const void* bhh  = d_in[7];
  const void* Wout = d_in[8];
  const void* bout = d_in[9];

  // workspace carve (~6.4 MiB), all offsets 256B-aligned
  char* ws = (char*)d_ws;
  int*      flagp  = (int*)(ws + 0);              //     256 B
  unsigned* bar    = (unsigned*)(ws + 256);       //   4,096 B: 16 leaves + root + gen
  float*    gi     = (float*)(ws + 4608);         // 786,432 B: [128][1536] f32
  __bf16*   hb0    = (__bf16*)(ws + 791040);      // 2,097,152 B: h bf16 ping
  __bf16*   hb1    = (__bf16*)(ws + 2888192);     // 2,097,152 B: h bf16 pong
  __bf16*   Whh_b  = (__bf16*)(ws + 4985344);     // 1,572,864 B
  __bf16*   Wout_b = (__bf16*)(ws + 6558208);     //   131,072 B
  float*    bhhn_f = (float*)(ws + 6689280);      //     2,048 B
  float*    bout_f = (float*)(ws + 6691328);      //       512 B

  probe_dtype<<<1, 256, 0, stream>>>((const unsigned short*)ehid, flagp, bar);
  conv_w<<<3072, 256, 0, stream>>>(Whh, Wout, bhh, bout, flagp,
                                   Whh_b, Wout_b, bhhn_f, bout_f);
  prep_gi<<<768, 256, 0, stream>>>(emb, Wih, bih, bhh, flagp, gi);
  prep_hb0<<<4096, 256, 0, stream>>>(ehid, flagp, hb0);

  gru_persist<<<640, 256, 0, stream>>>(Whh_b, Wout_b, bhhn_f, bout_f, gi, tgt,
                                       flagp, ehid, hb0, hb1, d_out, bar);
}

// Round 7
// 2855.227 us; speedup vs baseline: 4.8346x; 3.3274x over previous
//
#include <hip/hip_runtime.h>
#include <hip/hip_bf16.h>

typedef __bf16 bf16x8 __attribute__((ext_vector_type(8)));
typedef float  f32x4  __attribute__((ext_vector_type(4)));

#define MFMA_BF16(a, b, c) __builtin_amdgcn_mfma_f32_16x16x32_bf16((a), (b), (c), 0, 0, 0)

constexpr int TT = 160, BB = 2048, HH = 512, EE = 64, VV = 128, G3 = 1536;
constexpr size_t LPROB_ELEMS = (size_t)TT * BB * VV;  // 41,943,040

// phase-1 LDS: Whh tile [3 gates][16 rows][1024B + 16B pad]
constexpr int BSTRIDE = 1040;               // 1024 + 16 pad -> 2-way banks (free)
constexpr int GSZ = 16 * BSTRIDE;           // 16,640 B per gate
constexpr int SMEM_BYTES = 3 * GSZ;         // 49,920 B
// phase-2 LDS: Wout k-chunk [128 rows][256B + 8B pad] = 33,792 B, llds after
constexpr int WSTRIDE = 264;
constexpr int LLDS_OFF = 128 * WSTRIDE;     // 33,792

__device__ __forceinline__ float fsigmoid(float x) {
  return 1.0f / (1.0f + __expf(-x));
}
__device__ __forceinline__ float ftanh(float x) {
  float ax = fabsf(x);
  float e = __expf(-2.0f * ax);
  float r = (1.0f - e) / (1.0f + e);
  return x < 0.0f ? -r : r;
}
// dual-dtype scalar load: isbf ? bf16[i] : f32[i]
__device__ __forceinline__ float ld(const void* p, long i, int isbf) {
  return isbf ? (float)((const __bf16*)p)[i] : ((const float*)p)[i];
}

// ---------------- dtype probe ----------------
__global__ __launch_bounds__(256) void probe_dtype(
    const unsigned short* __restrict__ eh, int* __restrict__ flagp) {
  __shared__ int sb[256];
  int tid = threadIdx.x;
  int cnt = 0;
  for (int i = tid; i < 4096; i += 256) {
    unsigned short u = eh[i];
    int e = (u >> 7) & 0xFF;
    if ((u & 0x7FFF) == 0 || (e >= 90 && e <= 150)) cnt++;
  }
  sb[tid] = cnt;
  __syncthreads();
  for (int s = 128; s > 0; s >>= 1) {
    if (tid < s) sb[tid] += sb[tid + s];
    __syncthreads();
  }
  if (tid == 0) *flagp = (sb[0] > 3072) ? 1 : 0;
}

// ---------------- prep kernels ----------------
__global__ __launch_bounds__(256) void conv_w(
    const void* __restrict__ Whh, const void* __restrict__ Wout,
    const void* __restrict__ bhh, const void* __restrict__ bout,
    const int* __restrict__ flagp,
    __bf16* __restrict__ Whh_b, __bf16* __restrict__ Wout_b,
    float* __restrict__ bhhn_f, float* __restrict__ bout_f) {
  const int isbf = *flagp;
  int idx = blockIdx.x * 256 + threadIdx.x;   // 3072 blocks -> 786,432 = 1536*512
  Whh_b[idx] = (__bf16)ld(Whh, idx, isbf);
  if (idx < VV * HH) Wout_b[idx] = (__bf16)ld(Wout, idx, isbf);
  if (idx < HH) bhhn_f[idx] = ld(bhh, 2 * HH + idx, isbf);
  if (idx < VV) bout_f[idx] = ld(bout, idx, isbf);
}

// gi_vocab[v][n] = relu(emb[v]) . W_ih[n] + b_ih[n] + (n < 1024 ? b_hh[n] : 0)
__global__ __launch_bounds__(256) void prep_gi(
    const void* __restrict__ emb, const void* __restrict__ Wih,
    const void* __restrict__ bih, const void* __restrict__ bhh,
    const int* __restrict__ flagp, float* __restrict__ gi) {
  const int isbf = *flagp;
  int idx = blockIdx.x * 256 + threadIdx.x;   // 768 blocks -> exactly 128*1536
  int v = idx / G3;
  int n = idx - v * G3;
  float s = 0.0f;
#pragma unroll 8
  for (int k = 0; k < EE; ++k) {
    float x = ld(emb, v * EE + k, isbf);
    x = x > 0.0f ? x : 0.0f;
    s += x * ld(Wih, (long)n * EE + k, isbf);
  }
  s += ld(bih, n, isbf);
  if (n < 2 * HH) s += ld(bhh, n, isbf);
  gi[idx] = s;
}

// h0 = encoder_hidden[0]: fp32 state + bf16 mirror for MFMA
__global__ __launch_bounds__(256) void prep_h0(
    const void* __restrict__ ehid, const int* __restrict__ flagp,
    float* __restrict__ hf, __bf16* __restrict__ hb0) {
  const int isbf = *flagp;
  int idx = blockIdx.x * 256 + threadIdx.x;   // 4096 blocks -> 1,048,576
  float v = ld(ehid, idx, isbf);
  hf[idx] = v;
  hb0[idx] = (__bf16)v;
}

// ---------------- per-step kernel ----------------
// Grid 640 x 256, launched 161 times. Kernel boundary = device-wide sync.
// Blocks [0,512): phase 1 — grp=bid&15 owns rows grp*128..+128; colTile=bid>>4
//   owns output cols colTile*16..+16 of all 3 gates. B tile (49KB) LDS-staged
//   as an independent-load burst; epilogue inputs (tgt/gi/hf) prefetched before
//   the K-loop. Blocks [512,640): phase 2 — logits + log_softmax of h(t-1),
//   16 rows each; Wout staged in 4 K-chunks of 33KB; A-frags prefetched.
__global__ __launch_bounds__(256, 3) void gru_step(
    const __bf16* __restrict__ Whh, const __bf16* __restrict__ Wout,
    const float* __restrict__ bhhn_f, const float* __restrict__ bout_f,
    const float* __restrict__ gi, const int* __restrict__ tgt,
    const int* __restrict__ flagp,
    const __bf16* __restrict__ hbs,   // h(t-1) bf16
    __bf16* __restrict__ hbd,         // h(t) bf16 (written)
    float* __restrict__ hf,           // h f32, single buffer (own-element RMW)
    void* __restrict__ outp, int t) {
  __shared__ __align__(16) char smem[SMEM_BYTES];

  const int tid = threadIdx.x;
  const int bid = blockIdx.x;
  const int w = tid >> 6;
  const int lane = tid & 63;
  const int q = lane >> 4;
  const int l16 = lane & 15;
  const int isbf = *flagp;
  const f32x4 fzero = {0.0f, 0.0f, 0.0f, 0.0f};

  if (bid < 512) {
    if (t == 160) {
      // final hidden: outp[LPROB + idx] = hf[idx] in output dtype
      int base = bid * 2048 + tid * 8;
      const float* src = hf + base;
      if (isbf) {
        bf16x8 v;
#pragma unroll
        for (int i = 0; i < 8; ++i) v[i] = (__bf16)src[i];
        *(bf16x8*)((__bf16*)outp + LPROB_ELEMS + base) = v;
      } else {
        f32x4 v0 = *(const f32x4*)src;
        f32x4 v1 = *(const f32x4*)(src + 4);
        float* dst = (float*)outp + LPROB_ELEMS + base;
        *(f32x4*)dst = v0;
        *(f32x4*)(dst + 4) = v1;
      }
      return;
    }
    const int grp = bid & 15;
    const int colTile = bid >> 4;
    const int mBase = grp * 128 + w * 32;
    const int c = colTile * 16 + l16;
    const float bhhn = bhhn_f[c];

    // ---- stage B tile: Whh rows {g*512 + colTile*16 .. +16}, 49KB burst ----
    {
      const char* src0 = (const char*)(Whh + (size_t)(colTile * 16) * HH);
#pragma unroll
      for (int g = 0; g < 3; ++g) {
        const char* sg = src0 + (size_t)g * (HH * HH * 2);
#pragma unroll
        for (int j = 0; j < 4; ++j) {
          int off = (tid + j * 256) * 16;        // 0..16368
          bf16x8 v = *(const bf16x8*)(sg + off);
          *(bf16x8*)(smem + g * GSZ + (off >> 10) * BSTRIDE + (off & 1023)) = v;
        }
      }
    }

    // ---- prefetch epilogue inputs (independent of K-loop) ----
    int tk[2][4];
    float hold[2][4];
#pragma unroll
    for (int ms = 0; ms < 2; ++ms)
#pragma unroll
      for (int rg = 0; rg < 4; ++rg) {
        int row = mBase + ms * 16 + q * 4 + rg;
        tk[ms][rg] = (t == 0) ? 0 : tgt[row * TT + (t - 1)];
        hold[ms][rg] = hf[(size_t)row * HH + c];
      }
    float gv[2][4][3];
#pragma unroll
    for (int ms = 0; ms < 2; ++ms)
#pragma unroll
      for (int rg = 0; rg < 4; ++rg) {
        const float* gvp = gi + (size_t)tk[ms][rg] * G3 + c;
        gv[ms][rg][0] = gvp[0];
        gv[ms][rg][1] = gvp[HH];
        gv[ms][rg][2] = gvp[2 * HH];
      }
    __syncthreads();   // B tile staged

    // ---- gh = h(t-1) @ W_hh^T : A from global, B from LDS ----
    f32x4 acc[2][3];
#pragma unroll
    for (int ms = 0; ms < 2; ++ms)
#pragma unroll
      for (int gg = 0; gg < 3; ++gg) acc[ms][gg] = fzero;

    const __bf16* aRow0 = hbs + (size_t)(mBase + l16) * HH + q * 8;
    const __bf16* aRow1 = aRow0 + 16 * HH;
    const char* bb = smem + l16 * BSTRIDE + q * 16;

#pragma unroll 8
    for (int k0 = 0; k0 < HH; k0 += 32) {
      bf16x8 a0 = *(const bf16x8*)(aRow0 + k0);
      bf16x8 a1 = *(const bf16x8*)(aRow1 + k0);
#pragma unroll
      for (int gg = 0; gg < 3; ++gg) {
        bf16x8 bf = *(const bf16x8*)(bb + gg * GSZ + k0 * 2);
        acc[0][gg] = MFMA_BF16(a0, bf, acc[0][gg]);
        acc[1][gg] = MFMA_BF16(a1, bf, acc[1][gg]);
      }
    }

    // ---- GRU epilogue: everything already in registers ----
#pragma unroll
    for (int ms = 0; ms < 2; ++ms) {
#pragma unroll
      for (int rg = 0; rg < 4; ++rg) {
        int row = mBase + ms * 16 + q * 4 + rg;
        float r_ = fsigmoid(acc[ms][0][rg] + gv[ms][rg][0]);
        float z_ = fsigmoid(acc[ms][1][rg] + gv[ms][rg][1]);
        float n_ = ftanh(gv[ms][rg][2] + r_ * (acc[ms][2][rg] + bhhn));
        size_t hi = (size_t)row * HH + c;
        float hv = (1.0f - z_) * n_ + z_ * hold[ms][rg];
        hf[hi] = hv;
        hbd[hi] = (__bf16)hv;
      }
    }
  } else {
    // ---- phase 2: logits + log_softmax of h(t-1) ----
    if (t == 0) return;
    const int rb = (bid - 512) * 16;
    const __bf16* aR = hbs + (size_t)(rb + l16) * HH + q * 8;
    float* llds = (float*)(smem + LLDS_OFF);

    // prefetch all 16 A-fragments (A is only 16 rows x 512)
    bf16x8 afr[16];
#pragma unroll
    for (int i = 0; i < 16; ++i) afr[i] = *(const bf16x8*)(aR + i * 32);

    f32x4 acc2[2];
    acc2[0] = fzero; acc2[1] = fzero;
#pragma unroll
    for (int kc = 0; kc < 4; ++kc) {
      // stage Wout k-chunk: [128 rows][128 k] -> 32KB burst
#pragma unroll
      for (int j = 0; j < 8; ++j) {
        int off = (tid + j * 256) * 16;          // 0..32752
        int row = off >> 8;                      // /256
        int inrow = off & 255;
        bf16x8 v = *(const bf16x8*)((const char*)Wout +
                                    (size_t)row * 1024 + kc * 256 + inrow);
        *(bf16x8*)(smem + row * WSTRIDE + inrow) = v;
      }
      __syncthreads();
#pragma unroll
      for (int kl = 0; kl < 128; kl += 32) {
        bf16x8 a = afr[kc * 4 + (kl >> 5)];
        bf16x8 b0 = *(const bf16x8*)(smem + (w * 32 + l16) * WSTRIDE + kl * 2 + q * 16);
        bf16x8 b1 = *(const bf16x8*)(smem + (w * 32 + 16 + l16) * WSTRIDE + kl * 2 + q * 16);
        acc2[0] = MFMA_BF16(a, b0, acc2[0]);
        acc2[1] = MFMA_BF16(a, b1, acc2[1]);
      }
      __syncthreads();
    }

#pragma unroll
    for (int j = 0; j < 2; ++j) {
      int col = (w * 2 + j) * 16 + l16;
      float bo = bout_f[col];
#pragma unroll
      for (int rg = 0; rg < 4; ++rg)
        llds[(q * 4 + rg) * 132 + col] = acc2[j][rg] + bo;
    }
    __syncthreads();
    {
      int row = tid >> 4, seg = tid & 15;
      const float* lr = &llds[row * 132 + seg * 8];
      float x[8];
      float m = -3.0e38f;
#pragma unroll
      for (int i = 0; i < 8; ++i) { x[i] = lr[i]; m = fmaxf(m, x[i]); }
#pragma unroll
      for (int d = 1; d < 16; d <<= 1) m = fmaxf(m, __shfl_xor(m, d, 16));
      float s = 0.0f;
#pragma unroll
      for (int i = 0; i < 8; ++i) s += __expf(x[i] - m);
#pragma unroll
      for (int d = 1; d < 16; d <<= 1) s += __shfl_xor(s, d, 16);
      float lg = m + __logf(s);
      size_t ofs = (size_t)(t - 1) * (BB * VV) + (size_t)(rb + row) * VV + seg * 8;
      if (isbf) {
        bf16x8 ov;
#pragma unroll
        for (int i = 0; i < 8; ++i) ov[i] = (__bf16)(x[i] - lg);
        *(bf16x8*)((__bf16*)outp + ofs) = ov;
      } else {
        f32x4 o0, o1;
#pragma unroll
        for (int i = 0; i < 4; ++i) { o0[i] = x[i] - lg; o1[i] = x[4 + i] - lg; }
        float* dst = (float*)outp + ofs;
        *(f32x4*)dst = o0;
        *(f32x4*)(dst + 4) = o1;
      }
    }
  }
}

// ---------------- launcher ----------------
extern "C" void kernel_launch(void* const* d_in, const int* in_sizes, int n_in,
                              void* d_out, int out_size, void* d_ws, size_t ws_size,
                              hipStream_t stream) {
  // setup_inputs order:
  // 0 encoder_outputs (unused), 1 encoder_hidden, 2 target_tensor, 3 embedding,
  // 4 W_ih, 5 W_hh, 6 b_ih, 7 b_hh, 8 W_out, 9 b_out
  const void* ehid = d_in[1];
  const int*  tgt  = (const int*)d_in[2];
  const void* emb  = d_in[3];
  const void* Wih  = d_in[4];
  const void* Whh  = d_in[5];
  const void* bih  = d_in[6];
  const void* bhh  = d_in[7];
  const void* Wout = d_in[8];
  const void* bout = d_in[9];

  // workspace carve: ~10.4 MiB, all offsets 256B-aligned
  char* ws = (char*)d_ws;
  int*    flagp  = (int*)(ws + 0);              //       256 B
  float*  gi     = (float*)(ws + 256);          //   786,432 B: [128][1536] f32
  float*  hf     = (float*)(ws + 786688);       // 4,194,304 B: h f32
  __bf16* hb0    = (__bf16*)(ws + 4980992);     // 2,097,152 B: h bf16 ping
  __bf16* hb1    = (__bf16*)(ws + 7078144);     // 2,097,152 B: h bf16 pong
  __bf16* Whh_b  = (__bf16*)(ws + 9175296);     // 1,572,864 B
  __bf16* Wout_b = (__bf16*)(ws + 10748160);    //   131,072 B
  float*  bhhn_f = (float*)(ws + 10879232);     //     2,048 B
  float*  bout_f = (float*)(ws + 10881280);     //       512 B

  probe_dtype<<<1, 256, 0, stream>>>((const unsigned short*)ehid, flagp);
  conv_w<<<3072, 256, 0, stream>>>(Whh, Wout, bhh, bout, flagp,
                                   Whh_b, Wout_b, bhhn_f, bout_f);
  prep_gi<<<768, 256, 0, stream>>>(emb, Wih, bih, bhh, flagp, gi);
  prep_h0<<<4096, 256, 0, stream>>>(ehid, flagp, hf, hb0);

  for (int t = 0; t <= TT; ++t) {
    const __bf16* hbs = (t & 1) ? hb1 : hb0;   // h(t-1)
    __bf16*       hbd = (t & 1) ? hb0 : hb1;   // h(t)
    gru_step<<<640, 256, 0, stream>>>(Whh_b, Wout_b, bhhn_f, bout_f, gi, tgt,
                                      flagp, hbs, hbd, hf, d_out, t);
  }
}